// Round 1
// 429.617 us; speedup vs baseline: 1.0322x; 1.0322x over previous
//
#include <hip/hip_runtime.h>
#include <math.h>

#define SCALE 0.125f

typedef __bf16 bf16;
typedef __bf16 bf16x8 __attribute__((ext_vector_type(8)));
typedef float f32x4 __attribute__((ext_vector_type(4)));

// workspace byte offsets
#define WS_XB   0u            // x bf16:   4096*512*2          = 4 MB
#define WS_WB   4194304u      // Wq,Wk,Wv,Wo bf16: 4*512*512*2 = 2 MB
#define WS_Q    6291456u      // q  [b][h][n][d] bf16          = 4 MB
#define WS_K    10485760u     // k  [b][h][n][d] bf16          = 4 MB
#define WS_VT   14680064u     // vT [b][h][d][n] bf16          = 4 MB
#define WS_AT   18874368u     // attn out [b][n][h*64+d] bf16  = 4 MB

// ---------------- Kernel A: fp32 -> bf16 pack ----------------
__global__ __launch_bounds__(256) void convert_kernel(
    const float* __restrict__ x, const float* __restrict__ wq,
    const float* __restrict__ wk, const float* __restrict__ wv,
    const float* __restrict__ wo, bf16* __restrict__ xb, bf16* __restrict__ wb) {
  int i = blockIdx.x * 256 + threadIdx.x;  // float4 index; total 786432
  const float4* src; bf16* dst; int off;
  if (i < 524288) { src = (const float4*)x; dst = xb; off = i; }
  else {
    int j = i - 524288;
    int wsel = j >> 16; off = j & 65535;
    const float* wl = wsel == 0 ? wq : wsel == 1 ? wk : wsel == 2 ? wv : wo;
    src = (const float4*)wl; dst = wb + (wsel << 18);
  }
  float4 v = src[off];
  union { bf16 h[4]; uint2 u; } tmp;
  tmp.h[0] = (bf16)v.x; tmp.h[1] = (bf16)v.y;
  tmp.h[2] = (bf16)v.z; tmp.h[3] = (bf16)v.w;
  ((uint2*)dst)[off] = tmp.u;
}

// ---------------- Kernel B: QKV projection GEMM ----------------
// 128x64 tile, double-buffered LDS, ONE barrier per K-step.
// grid = 32 m-tiles x 24 n-tiles = 768 blocks (3/CU, balanced).
__global__ __launch_bounds__(256) void qkv_gemm(
    const bf16* __restrict__ xb, const bf16* __restrict__ wb,
    const float* __restrict__ bq, const float* __restrict__ bk,
    const float* __restrict__ bv, bf16* __restrict__ qws,
    bf16* __restrict__ kws, bf16* __restrict__ vtws) {
  __shared__ bf16 Al[2][128 * 40];
  __shared__ bf16 Bl[2][64 * 40];
  int t = threadIdx.x;
  int m0 = (blockIdx.x & 31) << 7;
  int n0 = (blockIdx.x >> 5) << 6;
  int lane = t & 63, w = t >> 6;
  int quad = lane >> 4, col = lane & 15;
  int mblk = (w >> 1) * 64, nblk = (w & 1) * 32;
  // staging: A 128 rows x 32 k (2 uint4/thread), B 64 rows x 32 k (1 uint4/thread)
  int arow = t >> 1, apart = (t & 1) << 1;
  int brow = t >> 2, bpart = t & 3;
  const bf16* ag = &xb[(m0 + arow) * 512 + apart * 8];
  const bf16* bg = &wb[(n0 + brow) * 512 + bpart * 8];
  f32x4 acc[4][2] = {};
  uint4 ra0 = *(const uint4*)ag;
  uint4 ra1 = *(const uint4*)(ag + 8);
  uint4 rb  = *(const uint4*)bg;
  for (int it = 0; it < 16; ++it) {
    int cur = it & 1;
    *(uint4*)&Al[cur][arow * 40 + apart * 8]     = ra0;
    *(uint4*)&Al[cur][arow * 40 + apart * 8 + 8] = ra1;
    *(uint4*)&Bl[cur][brow * 40 + bpart * 8]     = rb;
    if (it < 15) {
      int k0 = (it + 1) << 5;
      ra0 = *(const uint4*)(ag + k0);
      ra1 = *(const uint4*)(ag + k0 + 8);
      rb  = *(const uint4*)(bg + k0);
    }
    __syncthreads();
    bf16x8 af[4], bfv[2];
#pragma unroll
    for (int i = 0; i < 4; i++)
      af[i] = *(const bf16x8*)&Al[cur][(mblk + i * 16 + col) * 40 + quad * 8];
#pragma unroll
    for (int i = 0; i < 2; i++)
      bfv[i] = *(const bf16x8*)&Bl[cur][(nblk + i * 16 + col) * 40 + quad * 8];
#pragma unroll
    for (int mi = 0; mi < 4; mi++)
#pragma unroll
      for (int ni = 0; ni < 2; ni++)
        acc[mi][ni] = __builtin_amdgcn_mfma_f32_16x16x32_bf16(
            af[mi], bfv[ni], acc[mi][ni], 0, 0, 0);
  }
  for (int mi = 0; mi < 4; mi++)
    for (int ni = 0; ni < 2; ni++) {
      int n = n0 + nblk + ni * 16 + col;
      int wid = n >> 9, feat = n & 511;
      float bias = wid == 0 ? bq[feat] : wid == 1 ? bk[feat] : bv[feat];
      int h = feat >> 6, d = feat & 63;
      int mbase = m0 + mblk + mi * 16 + quad * 4;
      int bidx = mbase >> 11, seq0 = mbase & 2047;
      if (wid == 2) {
        // pack 4 consecutive seq into one 8B store (V^T layout [b][h][d][n])
        union { bf16 h4[4]; ushort4 u4; } pk;
        for (int r = 0; r < 4; r++) pk.h4[r] = (bf16)(acc[mi][ni][r] + bias);
        *(ushort4*)&vtws[(size_t)((((bidx << 3) + h) << 6) + d) * 2048 + seq0] = pk.u4;
      } else {
        bf16* dst = wid == 0 ? qws : kws;
        for (int r = 0; r < 4; r++)
          dst[(size_t)((((bidx << 3) + h) << 11) + seq0 + r) * 64 + d] =
              (bf16)(acc[mi][ni][r] + bias);
      }
    }
}

// ---------------- Kernel C: flash attention with geo bias ----------------
// one block = (b,h, 64-row Q tile); 4 waves, each wave owns 16 Q rows.
// K/V/bias LDS double-buffered (1 barrier/iter). Bias staged through a
// swizzled fp32 LDS tile (float4 loads) instead of 32 prefetch VGPRs.
__global__ __launch_bounds__(256, 2) void attn_kernel(
    const bf16* __restrict__ qws, const bf16* __restrict__ kws,
    const bf16* __restrict__ vtws, const float* __restrict__ gbias,
    bf16* __restrict__ attn) {
  __shared__ bf16 Kl[2][64 * 72];   // [buf][key][d]
  __shared__ bf16 Vl[2][64 * 72];   // [buf][d][key]
  __shared__ bf16 Pl[64 * 72];      // [qrow][key] (wave-private rows)
  __shared__ float Bb[2][64 * 64];  // [buf][qrow][key] swizzled: col^=((row>>2)&3)<<4
  int t = threadIdx.x, lane = t & 63, w = t >> 6;
  int quad = lane >> 4, col = lane & 15;
  int bh = blockIdx.x >> 5, qt = blockIdx.x & 31;
  int q0 = qt << 6;
  const bf16* qbase = qws + (size_t)bh * 2048 * 64;
  const bf16* kbase = kws + (size_t)bh * 2048 * 64;
  const bf16* vbase = vtws + (size_t)bh * 64 * 2048;
  const float* bb = gbias + ((size_t)bh * 2048 + q0) * 2048;

  // K/V staging: 4 threads per row, 16 bf16 (2 x uint4) each
  int srow = t >> 2, scol = (t & 3) << 4;
  // bias staging: thread -> (row group, float4 col); 4 rows per thread
  int brow0 = t >> 4, bcol4 = t & 15;

  // Q fragments (A-operand), per wave: rows w*16..w*16+15
  bf16x8 aq[2];
#pragma unroll
  for (int ks = 0; ks < 2; ++ks)
    aq[ks] = *(const bf16x8*)&qbase[(q0 + w * 16 + col) * 64 + ks * 32 + quad * 8];

  f32x4 o[4] = {};
  float mrow[4], lrow[4];
#pragma unroll
  for (int r = 0; r < 4; r++) { mrow[r] = -INFINITY; lrow[r] = 0.f; }

  // prologue: stage K/V/bias tile 0 into buf 0
  *(uint4*)&Kl[0][srow * 72 + scol]     = *(const uint4*)&kbase[srow * 64 + scol];
  *(uint4*)&Kl[0][srow * 72 + scol + 8] = *(const uint4*)&kbase[srow * 64 + scol + 8];
  *(uint4*)&Vl[0][srow * 72 + scol]     = *(const uint4*)&vbase[srow * 2048 + scol];
  *(uint4*)&Vl[0][srow * 72 + scol + 8] = *(const uint4*)&vbase[srow * 2048 + scol + 8];
#pragma unroll
  for (int p = 0; p < 4; ++p) {
    int row = brow0 + (p << 4);
    int sw = (row >> 2) & 3;
    *(float4*)&Bb[0][row * 64 + ((bcol4 ^ (sw << 2)) << 2)] =
        *(const float4*)&bb[(size_t)row * 2048 + (bcol4 << 2)];
  }
  __syncthreads();

  uint4 kra, krb, vra, vrb;
  float4 br4[4];
  for (int kt = 0; kt < 32; ++kt) {
    int cur = kt & 1, nb = cur ^ 1;
    bool pre = kt < 31;
    if (pre) {
      int snxt = (kt + 1) << 6;
      kra = *(const uint4*)&kbase[(snxt + srow) * 64 + scol];
      krb = *(const uint4*)&kbase[(snxt + srow) * 64 + scol + 8];
      vra = *(const uint4*)&vbase[srow * 2048 + snxt + scol];
      vrb = *(const uint4*)&vbase[srow * 2048 + snxt + scol + 8];
#pragma unroll
      for (int p = 0; p < 4; ++p)
        br4[p] = *(const float4*)&bb[(size_t)(brow0 + (p << 4)) * 2048 + snxt + (bcol4 << 2)];
    }

    // S = Q K^T from current LDS buffer
    f32x4 s[4];
    __builtin_amdgcn_s_setprio(1);
#pragma unroll
    for (int nt = 0; nt < 4; ++nt) {
      f32x4 a = {};
#pragma unroll
      for (int ks = 0; ks < 2; ++ks) {
        bf16x8 bk_ = *(const bf16x8*)&Kl[cur][(nt * 16 + col) * 72 + ks * 32 + quad * 8];
        a = __builtin_amdgcn_mfma_f32_16x16x32_bf16(aq[ks], bk_, a, 0, 0, 0);
      }
      s[nt] = a;
    }
    __builtin_amdgcn_s_setprio(0);

    // online softmax; bias read from swizzled LDS (2-way, conflict-free)
    int rbase = (w * 16 + quad * 4) * 64;
#pragma unroll
    for (int r = 0; r < 4; r++) {
      float sv[4];
#pragma unroll
      for (int nt = 0; nt < 4; nt++)
        sv[nt] = s[nt][r] * SCALE +
                 Bb[cur][rbase + r * 64 + ((nt ^ quad) << 4) + col];
      float mx = fmaxf(fmaxf(sv[0], sv[1]), fmaxf(sv[2], sv[3]));
#pragma unroll
      for (int d = 1; d < 16; d <<= 1) mx = fmaxf(mx, __shfl_xor(mx, d));
      // exact rescale-skip: if no row in the wave grew, alpha==1 identically
      if (!__all(mx <= mrow[r])) {
        float mnew = fmaxf(mrow[r], mx);
        float alpha = __expf(mrow[r] - mnew);
        mrow[r] = mnew;
        lrow[r] *= alpha;
#pragma unroll
        for (int dt = 0; dt < 4; ++dt) o[dt][r] *= alpha;
      }
      float sum = 0.f;
#pragma unroll
      for (int nt = 0; nt < 4; nt++) {
        float e = __expf(sv[nt] - mrow[r]);
        s[nt][r] = e;  // reuse s as P storage (cuts transient VGPRs)
        sum += e;
      }
#pragma unroll
      for (int d = 1; d < 16; d <<= 1) sum += __shfl_xor(sum, d);
      lrow[r] += sum;
    }

    // P -> LDS (wave-private rows; lgkmcnt only, no barrier needed)
#pragma unroll
    for (int nt = 0; nt < 4; nt++)
#pragma unroll
      for (int r = 0; r < 4; r++)
        Pl[(w * 16 + quad * 4 + r) * 72 + nt * 16 + col] = (bf16)s[nt][r];

    // O += P V from current buffer
    __builtin_amdgcn_s_setprio(1);
#pragma unroll
    for (int ks = 0; ks < 2; ++ks) {
      bf16x8 ap = *(const bf16x8*)&Pl[(w * 16 + col) * 72 + ks * 32 + quad * 8];
#pragma unroll
      for (int dt = 0; dt < 4; ++dt) {
        bf16x8 bv_ = *(const bf16x8*)&Vl[cur][(dt * 16 + col) * 72 + ks * 32 + quad * 8];
        o[dt] = __builtin_amdgcn_mfma_f32_16x16x32_bf16(ap, bv_, o[dt], 0, 0, 0);
      }
    }
    __builtin_amdgcn_s_setprio(0);

    // stage next K/V/bias into the other buffer
    if (pre) {
      *(uint4*)&Kl[nb][srow * 72 + scol]     = kra;
      *(uint4*)&Kl[nb][srow * 72 + scol + 8] = krb;
      *(uint4*)&Vl[nb][srow * 72 + scol]     = vra;
      *(uint4*)&Vl[nb][srow * 72 + scol + 8] = vrb;
#pragma unroll
      for (int p = 0; p < 4; ++p) {
        int row = brow0 + (p << 4);
        int sw = (row >> 2) & 3;
        *(float4*)&Bb[nb][row * 64 + ((bcol4 ^ (sw << 2)) << 2)] = br4[p];
      }
    }
    __syncthreads();
  }

  // finalize: divide by l, store [b][seq][h*64+d] bf16
  bf16* obase = attn + (size_t)(bh >> 3) * 2048 * 512 + (bh & 7) * 64;
  for (int r = 0; r < 4; r++) {
    float inv = 1.f / lrow[r];
    int gq = q0 + w * 16 + quad * 4 + r;
    for (int dt = 0; dt < 4; ++dt)
      obase[(size_t)gq * 512 + dt * 16 + col] = (bf16)(o[dt][r] * inv);
  }
}

// ---------------- Kernel D: output projection ----------------
// 128x64 tile, double-buffered, one barrier/K-step; grid 32x8 = 256 (full GPU).
__global__ __launch_bounds__(256) void out_gemm(
    const bf16* __restrict__ ab, const bf16* __restrict__ wob,
    const float* __restrict__ bo, float* __restrict__ out) {
  __shared__ bf16 Al[2][128 * 40];
  __shared__ bf16 Bl[2][64 * 40];
  int t = threadIdx.x;
  int m0 = (blockIdx.x & 31) << 7;
  int n0 = (blockIdx.x >> 5) << 6;
  int lane = t & 63, w = t >> 6;
  int quad = lane >> 4, col = lane & 15;
  int mblk = (w >> 1) * 64, nblk = (w & 1) * 32;
  int arow = t >> 1, apart = (t & 1) << 1;
  int brow = t >> 2, bpart = t & 3;
  const bf16* ag = &ab[(m0 + arow) * 512 + apart * 8];
  const bf16* bg = &wob[(n0 + brow) * 512 + bpart * 8];
  f32x4 acc[4][2] = {};
  uint4 ra0 = *(const uint4*)ag;
  uint4 ra1 = *(const uint4*)(ag + 8);
  uint4 rb  = *(const uint4*)bg;
  for (int it = 0; it < 16; ++it) {
    int cur = it & 1;
    *(uint4*)&Al[cur][arow * 40 + apart * 8]     = ra0;
    *(uint4*)&Al[cur][arow * 40 + apart * 8 + 8] = ra1;
    *(uint4*)&Bl[cur][brow * 40 + bpart * 8]     = rb;
    if (it < 15) {
      int k0 = (it + 1) << 5;
      ra0 = *(const uint4*)(ag + k0);
      ra1 = *(const uint4*)(ag + k0 + 8);
      rb  = *(const uint4*)(bg + k0);
    }
    __syncthreads();
    bf16x8 af[4], bfv[2];
#pragma unroll
    for (int i = 0; i < 4; i++)
      af[i] = *(const bf16x8*)&Al[cur][(mblk + i * 16 + col) * 40 + quad * 8];
#pragma unroll
    for (int i = 0; i < 2; i++)
      bfv[i] = *(const bf16x8*)&Bl[cur][(nblk + i * 16 + col) * 40 + quad * 8];
#pragma unroll
    for (int mi = 0; mi < 4; mi++)
#pragma unroll
      for (int ni = 0; ni < 2; ni++)
        acc[mi][ni] = __builtin_amdgcn_mfma_f32_16x16x32_bf16(
            af[mi], bfv[ni], acc[mi][ni], 0, 0, 0);
  }
  for (int mi = 0; mi < 4; mi++)
    for (int ni = 0; ni < 2; ni++)
      for (int r = 0; r < 4; r++) {
        int m = m0 + mblk + mi * 16 + quad * 4 + r;
        int n = n0 + nblk + ni * 16 + col;
        out[(size_t)m * 512 + n] = acc[mi][ni][r] + bo[n];
      }
}

extern "C" void kernel_launch(void* const* d_in, const int* in_sizes, int n_in,
                              void* d_out, int out_size, void* d_ws, size_t ws_size,
                              hipStream_t stream) {
  const float* x  = (const float*)d_in[0];
  const float* gb = (const float*)d_in[1];
  const float* Wq = (const float*)d_in[2];
  const float* bq = (const float*)d_in[3];
  const float* Wk = (const float*)d_in[4];
  const float* bk = (const float*)d_in[5];
  const float* Wv = (const float*)d_in[6];
  const float* bv = (const float*)d_in[7];
  const float* Wo = (const float*)d_in[8];
  const float* bo = (const float*)d_in[9];
  float* out = (float*)d_out;
  char* ws = (char*)d_ws;
  bf16* xb   = (bf16*)(ws + WS_XB);
  bf16* wb   = (bf16*)(ws + WS_WB);
  bf16* qws  = (bf16*)(ws + WS_Q);
  bf16* kws  = (bf16*)(ws + WS_K);
  bf16* vtws = (bf16*)(ws + WS_VT);
  bf16* at   = (bf16*)(ws + WS_AT);

  hipLaunchKernelGGL(convert_kernel, dim3(3072), dim3(256), 0, stream,
                     x, Wq, Wk, Wv, Wo, xb, wb);
  hipLaunchKernelGGL(qkv_gemm, dim3(768), dim3(256), 0, stream,
                     xb, wb, bq, bk, bv, qws, kws, vtws);
  hipLaunchKernelGGL(attn_kernel, dim3(512), dim3(256), 0, stream,
                     qws, kws, vtws, gb, at);
  hipLaunchKernelGGL(out_gemm, dim3(256), dim3(256), 0, stream,
                     at, wb + 3 * 262144, bo, out);
}

// Round 2
// 429.200 us; speedup vs baseline: 1.0332x; 1.0010x over previous
//
#include <hip/hip_runtime.h>
#include <math.h>

#define SCALE 0.125f

typedef __bf16 bf16;
typedef __bf16 bf16x8 __attribute__((ext_vector_type(8)));
typedef float f32x4 __attribute__((ext_vector_type(4)));
typedef unsigned int u32;

// async global -> LDS, 16B per lane; LDS dest = wave-uniform base + lane*16
__device__ __forceinline__ void gl_lds16(const void* g, void* l) {
  __builtin_amdgcn_global_load_lds(
      (const __attribute__((address_space(1))) u32*)g,
      (__attribute__((address_space(3))) u32*)l, 16, 0, 0);
}

// workspace byte offsets
#define WS_XB   0u            // x bf16:   4096*512*2          = 4 MB
#define WS_WB   4194304u      // Wq,Wk,Wv,Wo bf16: 4*512*512*2 = 2 MB
#define WS_Q    6291456u      // q  [b][h][n][d] bf16          = 4 MB
#define WS_K    10485760u     // k  [b][h][n][d] bf16          = 4 MB
#define WS_VT   14680064u     // vT [b][h][d][n] bf16          = 4 MB
#define WS_AT   18874368u     // attn out [b][n][h*64+d] bf16  = 4 MB

// ---------------- Kernel A: fp32 -> bf16 pack ----------------
__global__ __launch_bounds__(256) void convert_kernel(
    const float* __restrict__ x, const float* __restrict__ wq,
    const float* __restrict__ wk, const float* __restrict__ wv,
    const float* __restrict__ wo, bf16* __restrict__ xb, bf16* __restrict__ wb) {
  int i = blockIdx.x * 256 + threadIdx.x;  // float4 index; total 786432
  const float4* src; bf16* dst; int off;
  if (i < 524288) { src = (const float4*)x; dst = xb; off = i; }
  else {
    int j = i - 524288;
    int wsel = j >> 16; off = j & 65535;
    const float* wl = wsel == 0 ? wq : wsel == 1 ? wk : wsel == 2 ? wv : wo;
    src = (const float4*)wl; dst = wb + (wsel << 18);
  }
  float4 v = src[off];
  union { bf16 h[4]; uint2 u; } tmp;
  tmp.h[0] = (bf16)v.x; tmp.h[1] = (bf16)v.y;
  tmp.h[2] = (bf16)v.z; tmp.h[3] = (bf16)v.w;
  ((uint2*)dst)[off] = tmp.u;
}

// ---------------- Kernel B: QKV projection GEMM ----------------
// 128x64 tile, double-buffered LDS, ONE barrier per K-step. grid 32x24=768.
__global__ __launch_bounds__(256) void qkv_gemm(
    const bf16* __restrict__ xb, const bf16* __restrict__ wb,
    const float* __restrict__ bq, const float* __restrict__ bk,
    const float* __restrict__ bv, bf16* __restrict__ qws,
    bf16* __restrict__ kws, bf16* __restrict__ vtws) {
  __shared__ bf16 Al[2][128 * 40];
  __shared__ bf16 Bl[2][64 * 40];
  int t = threadIdx.x;
  int m0 = (blockIdx.x & 31) << 7;
  int n0 = (blockIdx.x >> 5) << 6;
  int lane = t & 63, w = t >> 6;
  int quad = lane >> 4, col = lane & 15;
  int mblk = (w >> 1) * 64, nblk = (w & 1) * 32;
  int arow = t >> 1, apart = (t & 1) << 1;
  int brow = t >> 2, bpart = t & 3;
  const bf16* ag = &xb[(m0 + arow) * 512 + apart * 8];
  const bf16* bg = &wb[(n0 + brow) * 512 + bpart * 8];
  f32x4 acc[4][2] = {};
  uint4 ra0 = *(const uint4*)ag;
  uint4 ra1 = *(const uint4*)(ag + 8);
  uint4 rb  = *(const uint4*)bg;
  for (int it = 0; it < 16; ++it) {
    int cur = it & 1;
    *(uint4*)&Al[cur][arow * 40 + apart * 8]     = ra0;
    *(uint4*)&Al[cur][arow * 40 + apart * 8 + 8] = ra1;
    *(uint4*)&Bl[cur][brow * 40 + bpart * 8]     = rb;
    if (it < 15) {
      int k0 = (it + 1) << 5;
      ra0 = *(const uint4*)(ag + k0);
      ra1 = *(const uint4*)(ag + k0 + 8);
      rb  = *(const uint4*)(bg + k0);
    }
    __syncthreads();
    bf16x8 af[4], bfv[2];
#pragma unroll
    for (int i = 0; i < 4; i++)
      af[i] = *(const bf16x8*)&Al[cur][(mblk + i * 16 + col) * 40 + quad * 8];
#pragma unroll
    for (int i = 0; i < 2; i++)
      bfv[i] = *(const bf16x8*)&Bl[cur][(nblk + i * 16 + col) * 40 + quad * 8];
#pragma unroll
    for (int mi = 0; mi < 4; mi++)
#pragma unroll
      for (int ni = 0; ni < 2; ni++)
        acc[mi][ni] = __builtin_amdgcn_mfma_f32_16x16x32_bf16(
            af[mi], bfv[ni], acc[mi][ni], 0, 0, 0);
  }
  for (int mi = 0; mi < 4; mi++)
    for (int ni = 0; ni < 2; ni++) {
      int n = n0 + nblk + ni * 16 + col;
      int wid = n >> 9, feat = n & 511;
      float bias = wid == 0 ? bq[feat] : wid == 1 ? bk[feat] : bv[feat];
      int h = feat >> 6, d = feat & 63;
      int mbase = m0 + mblk + mi * 16 + quad * 4;
      int bidx = mbase >> 11, seq0 = mbase & 2047;
      if (wid == 2) {
        union { bf16 h4[4]; ushort4 u4; } pk;
        for (int r = 0; r < 4; r++) pk.h4[r] = (bf16)(acc[mi][ni][r] + bias);
        *(ushort4*)&vtws[(size_t)((((bidx << 3) + h) << 6) + d) * 2048 + seq0] = pk.u4;
      } else {
        bf16* dst = wid == 0 ? qws : kws;
        for (int r = 0; r < 4; r++)
          dst[(size_t)((((bidx << 3) + h) << 11) + seq0 + r) * 64 + d] =
              (bf16)(acc[mi][ni][r] + bias);
      }
    }
}

// ---------------- Kernel C: flash attention with geo bias ----------------
// one block = (b,h, 64-row Q tile); 4 waves, each wave owns 16 Q rows.
// K/V/bias all staged via global_load_lds (DMA) into double-buffered,
// XOR-swizzled unpadded LDS tiles (rule-21: linear dest + inv-swz source +
// swz read). One barrier/iter; barrier's vmcnt(0) drain completes the DMA.
__global__ __launch_bounds__(256, 2) void attn_kernel(
    const bf16* __restrict__ qws, const bf16* __restrict__ kws,
    const bf16* __restrict__ vtws, const float* __restrict__ gbias,
    bf16* __restrict__ attn) {
  __shared__ bf16 Kl[2][64 * 64];   // [buf][key][d]; 16B chunk c holds g-chunk c^(key&7)
  __shared__ bf16 Vl[2][64 * 64];   // [buf][d][key]; same swizzle
  __shared__ float Bb[2][64 * 64];  // [buf][qrow][k]; dword col w holds g-col w^(((row>>2)&3)<<4)
  __shared__ bf16 Pl[64 * 72];      // [qrow][key] (wave-private rows)
  int t = threadIdx.x, lane = t & 63, w = t >> 6;
  int quad = lane >> 4, col = lane & 15;
  int bh = blockIdx.x >> 5, qt = blockIdx.x & 31;
  int q0 = qt << 6;
  const bf16* qbase = qws + (size_t)bh * 2048 * 64;
  const bf16* kbase = kws + (size_t)bh * 2048 * 64;
  const bf16* vbase = vtws + (size_t)bh * 64 * 2048;
  const float* bb = gbias + ((size_t)bh * 2048 + q0) * 2048;

  // DMA lane geometry: K/V call = 8 rows x 128B; bias call = 4 rows x 256B
  int lr = lane >> 3, lc = lane & 7, swc = lc ^ lr;
  int brow = lane >> 4, bw0 = (lane & 15) << 2;

  // Q fragments (A-operand), per wave: rows w*16..w*16+15
  bf16x8 aq[2];
#pragma unroll
  for (int ks = 0; ks < 2; ++ks)
    aq[ks] = *(const bf16x8*)&qbase[(q0 + w * 16 + col) * 64 + ks * 32 + quad * 8];

  f32x4 o[4] = {};
  f32x4 s[4];
  float mrow[4], lrow[4];
#pragma unroll
  for (int r = 0; r < 4; r++) { mrow[r] = -INFINITY; lrow[r] = 0.f; }

  // prologue: DMA tile 0 -> buf 0
#pragma unroll
  for (int c = 0; c < 2; ++c) {
    gl_lds16(&kbase[(size_t)(w * 16 + c * 8 + lr) * 64 + swc * 8],
             &Kl[0][(w * 16 + c * 8) * 64]);
    gl_lds16(&vbase[(size_t)(w * 16 + c * 8 + lr) * 2048 + swc * 8],
             &Vl[0][(w * 16 + c * 8) * 64]);
  }
#pragma unroll
  for (int c = 0; c < 4; ++c)
    gl_lds16(&bb[(size_t)(w * 16 + c * 4 + brow) * 2048 + (bw0 ^ (c << 4))],
             &Bb[0][(w * 16 + c * 4) * 64]);
  __syncthreads();

  for (int kt = 0; kt < 32; ++kt) {
    int cur = kt & 1, nb = cur ^ 1;
    // issue next-tile DMA into the other buffer (drains at this iter's barrier)
    if (kt < 31) {
      int s0 = (kt + 1) << 6;
#pragma unroll
      for (int c = 0; c < 2; ++c) {
        gl_lds16(&kbase[(size_t)(s0 + w * 16 + c * 8 + lr) * 64 + swc * 8],
                 &Kl[nb][(w * 16 + c * 8) * 64]);
        gl_lds16(&vbase[(size_t)(w * 16 + c * 8 + lr) * 2048 + s0 + swc * 8],
                 &Vl[nb][(w * 16 + c * 8) * 64]);
      }
#pragma unroll
      for (int c = 0; c < 4; ++c)
        gl_lds16(&bb[(size_t)(w * 16 + c * 4 + brow) * 2048 + s0 + (bw0 ^ (c << 4))],
                 &Bb[nb][(w * 16 + c * 4) * 64]);
    }

    // S = Q K^T from current buffer (swizzled read: chunk ^= key&7)
    __builtin_amdgcn_s_setprio(1);
#pragma unroll
    for (int nt = 0; nt < 4; ++nt) {
      f32x4 a = {};
#pragma unroll
      for (int ks = 0; ks < 2; ++ks) {
        bf16x8 bk_ = *(const bf16x8*)&Kl[cur][(nt * 16 + col) * 64 +
                                              (((ks * 4 + quad) ^ (col & 7)) << 3)];
        a = __builtin_amdgcn_mfma_f32_16x16x32_bf16(aq[ks], bk_, a, 0, 0, 0);
      }
      s[nt] = a;
    }
    __builtin_amdgcn_s_setprio(0);

    // online softmax; bias from swizzled LDS (2-way reads, free)
    int rb = (w * 16 + quad * 4) * 64;
#pragma unroll
    for (int r = 0; r < 4; r++) {
      float sv[4];
#pragma unroll
      for (int nt = 0; nt < 4; nt++)
        sv[nt] = s[nt][r] * SCALE + Bb[cur][rb + r * 64 + (((nt ^ quad) << 4) | col)];
      float mx = fmaxf(fmaxf(sv[0], sv[1]), fmaxf(sv[2], sv[3]));
#pragma unroll
      for (int d = 1; d < 16; d <<= 1) mx = fmaxf(mx, __shfl_xor(mx, d));
      // exact rescale-skip: rows that didn't grow get alpha==1 identically
      if (!__all(mx <= mrow[r])) {
        float mnew = fmaxf(mrow[r], mx);
        float alpha = __expf(mrow[r] - mnew);
        mrow[r] = mnew;
        lrow[r] *= alpha;
#pragma unroll
        for (int dt = 0; dt < 4; ++dt) o[dt][r] *= alpha;
      }
      float ls = 0.f;
#pragma unroll
      for (int nt = 0; nt < 4; nt++) {
        float e = __expf(sv[nt] - mrow[r]);
        s[nt][r] = e;  // reuse s as P storage
        ls += e;
      }
      lrow[r] += ls;  // lane-partial denominator; reduced once at finalize
    }

    // P -> LDS (wave-private rows; in-order DS pipe, no barrier needed)
#pragma unroll
    for (int nt = 0; nt < 4; nt++)
#pragma unroll
      for (int r = 0; r < 4; r++)
        Pl[(w * 16 + quad * 4 + r) * 72 + nt * 16 + col] = (bf16)s[nt][r];

    // O += P V from current buffer
    __builtin_amdgcn_s_setprio(1);
#pragma unroll
    for (int ks = 0; ks < 2; ++ks) {
      bf16x8 ap = *(const bf16x8*)&Pl[(w * 16 + col) * 72 + ks * 32 + quad * 8];
#pragma unroll
      for (int dt = 0; dt < 4; ++dt) {
        bf16x8 bv_ = *(const bf16x8*)&Vl[cur][(dt * 16 + col) * 64 +
                                              (((ks * 4 + quad) ^ (col & 7)) << 3)];
        o[dt] = __builtin_amdgcn_mfma_f32_16x16x32_bf16(ap, bv_, o[dt], 0, 0, 0);
      }
    }
    __builtin_amdgcn_s_setprio(0);
    __syncthreads();
  }

  // finalize: reduce lane-partial l across the 16 col-lanes, divide, store
  bf16* obase = attn + (size_t)(bh >> 3) * 2048 * 512 + (bh & 7) * 64;
#pragma unroll
  for (int r = 0; r < 4; r++) {
#pragma unroll
    for (int d = 1; d < 16; d <<= 1) lrow[r] += __shfl_xor(lrow[r], d);
    float inv = 1.f / lrow[r];
    int gq = q0 + w * 16 + quad * 4 + r;
#pragma unroll
    for (int dt = 0; dt < 4; ++dt)
      obase[(size_t)gq * 512 + dt * 16 + col] = (bf16)(o[dt][r] * inv);
  }
}

// ---------------- Kernel D: output projection ----------------
// 128x64 tile, double-buffered, one barrier/K-step; grid 32x8 = 256.
__global__ __launch_bounds__(256) void out_gemm(
    const bf16* __restrict__ ab, const bf16* __restrict__ wob,
    const float* __restrict__ bo, float* __restrict__ out) {
  __shared__ bf16 Al[2][128 * 40];
  __shared__ bf16 Bl[2][64 * 40];
  int t = threadIdx.x;
  int m0 = (blockIdx.x & 31) << 7;
  int n0 = (blockIdx.x >> 5) << 6;
  int lane = t & 63, w = t >> 6;
  int quad = lane >> 4, col = lane & 15;
  int mblk = (w >> 1) * 64, nblk = (w & 1) * 32;
  int arow = t >> 1, apart = (t & 1) << 1;
  int brow = t >> 2, bpart = t & 3;
  const bf16* ag = &ab[(m0 + arow) * 512 + apart * 8];
  const bf16* bg = &wob[(n0 + brow) * 512 + bpart * 8];
  f32x4 acc[4][2] = {};
  uint4 ra0 = *(const uint4*)ag;
  uint4 ra1 = *(const uint4*)(ag + 8);
  uint4 rb  = *(const uint4*)bg;
  for (int it = 0; it < 16; ++it) {
    int cur = it & 1;
    *(uint4*)&Al[cur][arow * 40 + apart * 8]     = ra0;
    *(uint4*)&Al[cur][arow * 40 + apart * 8 + 8] = ra1;
    *(uint4*)&Bl[cur][brow * 40 + bpart * 8]     = rb;
    if (it < 15) {
      int k0 = (it + 1) << 5;
      ra0 = *(const uint4*)(ag + k0);
      ra1 = *(const uint4*)(ag + k0 + 8);
      rb  = *(const uint4*)(bg + k0);
    }
    __syncthreads();
    bf16x8 af[4], bfv[2];
#pragma unroll
    for (int i = 0; i < 4; i++)
      af[i] = *(const bf16x8*)&Al[cur][(mblk + i * 16 + col) * 40 + quad * 8];
#pragma unroll
    for (int i = 0; i < 2; i++)
      bfv[i] = *(const bf16x8*)&Bl[cur][(nblk + i * 16 + col) * 40 + quad * 8];
#pragma unroll
    for (int mi = 0; mi < 4; mi++)
#pragma unroll
      for (int ni = 0; ni < 2; ni++)
        acc[mi][ni] = __builtin_amdgcn_mfma_f32_16x16x32_bf16(
            af[mi], bfv[ni], acc[mi][ni], 0, 0, 0);
  }
  for (int mi = 0; mi < 4; mi++)
    for (int ni = 0; ni < 2; ni++)
      for (int r = 0; r < 4; r++) {
        int m = m0 + mblk + mi * 16 + quad * 4 + r;
        int n = n0 + nblk + ni * 16 + col;
        out[(size_t)m * 512 + n] = acc[mi][ni][r] + bo[n];
      }
}

extern "C" void kernel_launch(void* const* d_in, const int* in_sizes, int n_in,
                              void* d_out, int out_size, void* d_ws, size_t ws_size,
                              hipStream_t stream) {
  const float* x  = (const float*)d_in[0];
  const float* gb = (const float*)d_in[1];
  const float* Wq = (const float*)d_in[2];
  const float* bq = (const float*)d_in[3];
  const float* Wk = (const float*)d_in[4];
  const float* bk = (const float*)d_in[5];
  const float* Wv = (const float*)d_in[6];
  const float* bv = (const float*)d_in[7];
  const float* Wo = (const float*)d_in[8];
  const float* bo = (const float*)d_in[9];
  float* out = (float*)d_out;
  char* ws = (char*)d_ws;
  bf16* xb   = (bf16*)(ws + WS_XB);
  bf16* wb   = (bf16*)(ws + WS_WB);
  bf16* qws  = (bf16*)(ws + WS_Q);
  bf16* kws  = (bf16*)(ws + WS_K);
  bf16* vtws = (bf16*)(ws + WS_VT);
  bf16* at   = (bf16*)(ws + WS_AT);

  hipLaunchKernelGGL(convert_kernel, dim3(3072), dim3(256), 0, stream,
                     x, Wq, Wk, Wv, Wo, xb, wb);
  hipLaunchKernelGGL(qkv_gemm, dim3(768), dim3(256), 0, stream,
                     xb, wb, bq, bk, bv, qws, kws, vtws);
  hipLaunchKernelGGL(attn_kernel, dim3(512), dim3(256), 0, stream,
                     qws, kws, vtws, gb, at);
  hipLaunchKernelGGL(out_gemm, dim3(256), dim3(256), 0, stream,
                     at, wb + 3 * 262144, bo, out);
}